// Round 1
// baseline (561.470 us; speedup 1.0000x reference)
//
#include <hip/hip_runtime.h>

// Attention_884763263569 on gfx950 — v3.
// x:[65536,3,512] f32, Wk/Wv:[32,512], Wq:[32,1536], Wfc:[10,32], bfc:[10] -> out [65536,10] f32.
//
// Folding: out = sum_t a_t * (Wfc@Wv @ x_t) + bfc  ->  Wvf = Wfc@Wv [10,512].
// Combined per-t logical weight rows (80, fp16): 0..31 Wk | 32..63 Wq slice t | 64..73 Wvf | 74..79 zero.
// v3 changes vs v2:
//  * K-PERMUTED fragments: lane quad q holds k in {4q..4q+3} U {16+4q..16+4q+3}. Both x-load
//    instructions now cover 16 FULL 64B lines each (no split-line double-touch under nt loads).
//    build_weights packs B with the matching permutation, so the MFMA result is unchanged.
//  * M_TILES=1 (16 samples/wave) + q-accumulator shared across t (q = sum_t Wq_t x_t):
//    acc drops 120 -> 44 VGPRs; grid 512 -> 1024 blocks -> 16 waves/CU (4/SIMD) for latency hiding.
//  Zero LDS, zero barriers.

typedef __attribute__((ext_vector_type(4))) float  f32x4;
typedef __attribute__((ext_vector_type(8))) _Float16 h16x8;

#define T_VIEWS 3
#define D_DIM   512
#define P_DIM   32
#define C_DIM   10
#define NROWS   80          // padded logical rows per t
#define NT      5           // n-tiles of 16
#define KC      16          // k-chunks of 32
#define WAVES_PER_BLOCK 4
#define SAMPLES_PER_BLOCK (16 * WAVES_PER_BLOCK)   // 64

// ---------------- Kernel A: build fragment-ordered fp16 weights in d_ws ----------------
// Logical (t, j, d) -> frag addr (((t*KC+kc)*NT+n)*64 + quad*16+col)*8 + jj
// K-permutation within a 32-chunk: r = d&31 maps to quad=(r>>2)&3, jj=((r>>4)<<2)|(r&3),
// i.e. element jj of quad q is k = (jj<4 ? 4q+jj : 16+4q+jj-4). Matches the A-side loads below.
__global__ void build_weights(const float* __restrict__ Wk,
                              const float* __restrict__ Wv,
                              const float* __restrict__ Wq,
                              const float* __restrict__ Wfc,
                              _Float16* __restrict__ Wf) {
    const int row = blockIdx.x;          // 0 .. 3*80-1
    const int t   = row / NROWS;
    const int j   = row % NROWS;
    const int d   = threadIdx.x;         // 0..511
    float val;
    if (j < 32) {
        val = Wk[j * D_DIM + d];
    } else if (j < 64) {
        const int p = j - 32;
        val = Wq[p * (T_VIEWS * D_DIM) + t * D_DIM + d];
    } else if (j < 64 + C_DIM) {
        const int i = j - 64;
        float s = 0.f;
        #pragma unroll
        for (int p = 0; p < P_DIM; ++p)
            s += Wfc[i * P_DIM + p] * Wv[p * D_DIM + d];
        val = s;
    } else {
        val = 0.f;                        // pad rows (d_ws is poisoned -> must zero)
    }
    const int n = j >> 4, coln = j & 15;
    const int kc = d >> 5, r = d & 31;
    const int quad = (r >> 2) & 3;                 // K-permuted quad
    const int jj   = ((r >> 4) << 2) | (r & 3);    // K-permuted element index
    const size_t addr = (size_t)((((t * KC + kc) * NT + n) * 64) + quad * 16 + coln) * 8 + jj;
    Wf[addr] = (_Float16)val;
}

// ---------------- Main fused kernel ----------------
__global__ __launch_bounds__(256, 4) void attn_fused(
        const float* __restrict__ x,
        const _Float16* __restrict__ Wf,
        const float* __restrict__ bfc,
        float* __restrict__ out) {
    const int lane = threadIdx.x & 63;
    const int wave = threadIdx.x >> 6;
    const int col  = lane & 15;          // MFMA: A-row m (sample) / B-col n / C-col
    const int quad = lane >> 4;          // MFMA: k-group / C row-group
    const int row_base = blockIdx.x * SAMPLES_PER_BLOCK + wave * 16;

    // accumulators: k per-t (2 halves), q SHARED across t (summed via MFMA C-chain), yv per-t
    f32x4 acc_k[3][2];
    f32x4 acc_q[2];
    f32x4 acc_y[3];
    #pragma unroll
    for (int t = 0; t < 3; ++t) {
        acc_k[t][0] = (f32x4)0.f;
        acc_k[t][1] = (f32x4)0.f;
        acc_y[t]    = (f32x4)0.f;
    }
    acc_q[0] = (f32x4)0.f;
    acc_q[1] = (f32x4)0.f;

    // A-operand base: lane (col,quad) -> sample row = col; k-permuted:
    //   x0 @ +quad*4 floats (k = 4q..4q+3), x1 @ +64B further (k = 16+4q..16+4q+3).
    // Each x-load instruction covers 16 full 64B lines, each line touched exactly once.
    const float* xbase = x + (size_t)(row_base + col) * (T_VIEWS * D_DIM) + quad * 4;
    const _Float16* wt = Wf + lane * 8;

    #pragma unroll
    for (int t = 0; t < 3; ++t) {
        #pragma unroll 2
        for (int kc = 0; kc < KC; ++kc) {
            h16x8 b[NT];
            #pragma unroll
            for (int n = 0; n < NT; ++n)
                b[n] = *(const h16x8*)(wt + (size_t)(((t * KC + kc) * NT + n)) * 512);
            const float* xp = xbase + t * D_DIM + kc * 32;
            const f32x4 x0 = __builtin_nontemporal_load((const f32x4*)xp);
            const f32x4 x1 = __builtin_nontemporal_load((const f32x4*)(xp + 16));
            h16x8 a;
            #pragma unroll
            for (int i = 0; i < 4; ++i) {
                a[i]     = (_Float16)x0[i];
                a[i + 4] = (_Float16)x1[i];
            }
            acc_k[t][0] = __builtin_amdgcn_mfma_f32_16x16x32_f16(a, b[0], acc_k[t][0], 0, 0, 0);
            acc_k[t][1] = __builtin_amdgcn_mfma_f32_16x16x32_f16(a, b[1], acc_k[t][1], 0, 0, 0);
            acc_q[0]    = __builtin_amdgcn_mfma_f32_16x16x32_f16(a, b[2], acc_q[0],    0, 0, 0);
            acc_q[1]    = __builtin_amdgcn_mfma_f32_16x16x32_f16(a, b[3], acc_q[1],    0, 0, 0);
            acc_y[t]    = __builtin_amdgcn_mfma_f32_16x16x32_f16(a, b[4], acc_y[t],    0, 0, 0);
        }
    }

    // ---------------- Epilogue (registers + shfl only) ----------------
    // C layout: element r holds sample row (quad*4 + r), column (n*16 + col).
    const float bias = (col < C_DIM) ? bfc[col] : 0.f;

    float outv[4];
    #pragma unroll
    for (int r = 0; r < 4; ++r) {
        const float qa = acc_q[0][r];     // q[sample][p=col]
        const float qb = acc_q[1][r];     // q[sample][p=16+col]
        float s0 = qa * acc_k[0][0][r] + qb * acc_k[0][1][r];
        float s1 = qa * acc_k[1][0][r] + qb * acc_k[1][1][r];
        float s2 = qa * acc_k[2][0][r] + qb * acc_k[2][1][r];
        #pragma unroll
        for (int msk = 1; msk <= 8; msk <<= 1) {
            s0 += __shfl_xor(s0, msk, 64);
            s1 += __shfl_xor(s1, msk, 64);
            s2 += __shfl_xor(s2, msk, 64);
        }
        const float mx = fmaxf(s0, fmaxf(s1, s2));
        const float e0 = __expf(s0 - mx);
        const float e1 = __expf(s1 - mx);
        const float e2 = __expf(s2 - mx);
        const float inv = 1.f / (e0 + e1 + e2);
        outv[r] = (e0 * acc_y[0][r] + e1 * acc_y[1][r] + e2 * acc_y[2][r]) * inv + bias;
    }
    if (col < C_DIM) {
        const int b0 = row_base + quad * 4;
        #pragma unroll
        for (int r = 0; r < 4; ++r)
            out[(size_t)(b0 + r) * C_DIM + col] = outv[r];
    }
}

extern "C" void kernel_launch(void* const* d_in, const int* in_sizes, int n_in,
                              void* d_out, int out_size, void* d_ws, size_t ws_size,
                              hipStream_t stream) {
    const float* x   = (const float*)d_in[0];
    const float* Wk  = (const float*)d_in[1];
    const float* Wv  = (const float*)d_in[2];
    const float* Wq  = (const float*)d_in[3];
    const float* Wfc = (const float*)d_in[4];
    const float* bfc = (const float*)d_in[5];
    _Float16* Wf = (_Float16*)d_ws;       // 3*80*512 halfs = 240 KB, fragment-ordered

    hipLaunchKernelGGL(build_weights, dim3(T_VIEWS * NROWS), dim3(D_DIM), 0, stream,
                       Wk, Wv, Wq, Wfc, Wf);

    const int B_TOTAL = in_sizes[0] / (T_VIEWS * D_DIM);      // 65536
    const int blocks = B_TOTAL / SAMPLES_PER_BLOCK;           // 1024
    hipLaunchKernelGGL(attn_fused, dim3(blocks), dim3(256), 0, stream,
                       x, Wf, bfc, (float*)d_out);
}

// Round 2
// 533.238 us; speedup vs baseline: 1.0529x; 1.0529x over previous
//
#include <hip/hip_runtime.h>

// Attention_884763263569 on gfx950 — v4.
// x:[65536,3,512] f32, Wk/Wv:[32,512], Wq:[32,1536], Wfc:[10,32], bfc:[10] -> out [65536,10] f32.
//
// Folding: out = sum_t a_t * (Wfc@Wv @ x_t) + bfc  ->  Wvf = Wfc@Wv [10,512].
// Combined per-t logical weight rows (80, fp16): 0..31 Wk | 32..63 Wq slice t | 64..73 Wvf | 74..79 zero.
// v4 changes vs v3:
//  * Wf staged into LDS cooperatively (global_load_lds, 16B) in double-buffered 20 KB
//    super-chunks covering 4 k-steps each. Each block reads Wf ONCE (240 KB) instead of
//    once per wave (4x traffic cut); inner loop B-reads become conflict-free ds_read_b128.
//  * One __syncthreads per super-chunk (12 total); the 4-step body is barrier-free so the
//    compiler can pipeline the 8 x-loads deep. VMEM per k-step: 7 -> ~3.25 instructions.
//  * Keeps v3's K-permuted fragments (full-line x loads) and shared-q accumulator.
//  LDS 40 KB/block -> 4 blocks/CU -> 16 waves/CU with __launch_bounds__(256,4).

typedef __attribute__((ext_vector_type(4))) float  f32x4;
typedef __attribute__((ext_vector_type(8))) _Float16 h16x8;

#define T_VIEWS 3
#define D_DIM   512
#define P_DIM   32
#define C_DIM   10
#define NROWS   80          // padded logical rows per t
#define NT      5           // n-tiles of 16
#define KC      16          // k-chunks of 32
#define NSTEPS  48          // T_VIEWS*KC k-steps total
#define JPER    4           // k-steps per LDS super-chunk
#define NSUPER  (NSTEPS/JPER)            // 12
#define STEP_B  (NT*1024)                // 5120 B of fragments per k-step
#define CHUNK_B (JPER*STEP_B)            // 20480 B per super-chunk
#define WAVES_PER_BLOCK 4
#define SAMPLES_PER_BLOCK (16 * WAVES_PER_BLOCK)   // 64

// ---------------- Kernel A: build fragment-ordered fp16 weights in d_ws ----------------
// Logical (t, j, d) -> frag addr (((t*KC+kc)*NT+n)*64 + quad*16+col)*8 + jj
// K-permutation within a 32-chunk: r = d&31 maps to quad=(r>>2)&3, jj=((r>>4)<<2)|(r&3),
// i.e. element jj of quad q is k = (jj<4 ? 4q+jj : 16+4q+jj-4). Matches the A-side loads below.
__global__ void build_weights(const float* __restrict__ Wk,
                              const float* __restrict__ Wv,
                              const float* __restrict__ Wq,
                              const float* __restrict__ Wfc,
                              _Float16* __restrict__ Wf) {
    const int row = blockIdx.x;          // 0 .. 3*80-1
    const int t   = row / NROWS;
    const int j   = row % NROWS;
    const int d   = threadIdx.x;         // 0..511
    float val;
    if (j < 32) {
        val = Wk[j * D_DIM + d];
    } else if (j < 64) {
        const int p = j - 32;
        val = Wq[p * (T_VIEWS * D_DIM) + t * D_DIM + d];
    } else if (j < 64 + C_DIM) {
        const int i = j - 64;
        float s = 0.f;
        #pragma unroll
        for (int p = 0; p < P_DIM; ++p)
            s += Wfc[i * P_DIM + p] * Wv[p * D_DIM + d];
        val = s;
    } else {
        val = 0.f;                        // pad rows (d_ws is poisoned -> must zero)
    }
    const int n = j >> 4, coln = j & 15;
    const int kc = d >> 5, r = d & 31;
    const int quad = (r >> 2) & 3;                 // K-permuted quad
    const int jj   = ((r >> 4) << 2) | (r & 3);    // K-permuted element index
    const size_t addr = (size_t)((((t * KC + kc) * NT + n) * 64) + quad * 16 + coln) * 8 + jj;
    Wf[addr] = (_Float16)val;
}

// ---------------- Main fused kernel ----------------
__global__ __launch_bounds__(256, 4) void attn_fused(
        const float* __restrict__ x,
        const _Float16* __restrict__ Wf,
        const float* __restrict__ bfc,
        float* __restrict__ out) {
    __shared__ char lds[2 * CHUNK_B];    // 40 KB double-buffered fragment store

    const int lane = threadIdx.x & 63;
    const int wave = threadIdx.x >> 6;
    const int col  = lane & 15;          // MFMA: A-row m (sample) / B-col n / C-col
    const int quad = lane >> 4;          // MFMA: k-group / C row-group
    const int row_base = blockIdx.x * SAMPLES_PER_BLOCK + wave * 16;

    // accumulators: k per-t (2 halves), q SHARED across t (summed via MFMA C-chain), yv per-t
    f32x4 acc_k[3][2];
    f32x4 acc_q[2];
    f32x4 acc_y[3];
    #pragma unroll
    for (int t = 0; t < 3; ++t) {
        acc_k[t][0] = (f32x4)0.f;
        acc_k[t][1] = (f32x4)0.f;
        acc_y[t]    = (f32x4)0.f;
    }
    acc_q[0] = (f32x4)0.f;
    acc_q[1] = (f32x4)0.f;

    // A-operand: lane (col,quad) -> sample row = col; k-permuted:
    //   x0 @ +quad*4 floats (k = 4q..4q+3), x1 @ +64B further (k = 16+4q..16+4q+3).
    // Each x-load instruction covers 16 full 64B lines, each line touched exactly once.
    const float* xbase = x + (size_t)(row_base + col) * (T_VIEWS * D_DIM) + quad * 4;
    const char*  wf   = (const char*)Wf + lane * 16;   // per-lane global src for staging

    // ---- prologue: stage super-chunk 0 (all 4 waves split the 20 glds calls) ----
    #pragma unroll
    for (int i = 0; i < 5; ++i) {
        const int idx = wave * 5 + i;                  // 0..19, 1 KB each
        __builtin_amdgcn_global_load_lds(
            (const __attribute__((address_space(1))) void*)(wf + (size_t)idx * 1024),
            (__attribute__((address_space(3))) void*)(lds + idx * 1024),
            16, 0, 0);
    }
    __syncthreads();

    for (int u = 0; u < NSUPER; ++u) {
        const int cbuf = u & 1;
        const int nbuf = cbuf ^ 1;
        // stage next super-chunk into the other buffer (loads stay in flight under compute)
        if (u + 1 < NSUPER) {
            #pragma unroll
            for (int i = 0; i < 5; ++i) {
                const int idx = wave * 5 + i;
                const size_t gb = (size_t)(u + 1) * CHUNK_B + (size_t)idx * 1024;
                __builtin_amdgcn_global_load_lds(
                    (const __attribute__((address_space(1))) void*)(wf + gb),
                    (__attribute__((address_space(3))) void*)(lds + nbuf * CHUNK_B + idx * 1024),
                    16, 0, 0);
            }
        }
        // barrier-free 4-step body: compiler pipelines the 8 x-loads + 20 ds_reads
        #pragma unroll
        for (int j = 0; j < JPER; ++j) {
            const int s  = u * JPER + j;
            const int t  = s >> 4;
            const int kc = s & 15;
            const float* xp = xbase + t * D_DIM + kc * 32;
            const f32x4 x0 = __builtin_nontemporal_load((const f32x4*)xp);
            const f32x4 x1 = __builtin_nontemporal_load((const f32x4*)(xp + 16));
            h16x8 b[NT];
            #pragma unroll
            for (int n = 0; n < NT; ++n)
                b[n] = *(const h16x8*)(lds + cbuf * CHUNK_B + j * STEP_B + n * 1024 + lane * 16);
            h16x8 a;
            #pragma unroll
            for (int i = 0; i < 4; ++i) {
                a[i]     = (_Float16)x0[i];
                a[i + 4] = (_Float16)x1[i];
            }
            acc_k[t][0] = __builtin_amdgcn_mfma_f32_16x16x32_f16(a, b[0], acc_k[t][0], 0, 0, 0);
            acc_k[t][1] = __builtin_amdgcn_mfma_f32_16x16x32_f16(a, b[1], acc_k[t][1], 0, 0, 0);
            acc_q[0]    = __builtin_amdgcn_mfma_f32_16x16x32_f16(a, b[2], acc_q[0],    0, 0, 0);
            acc_q[1]    = __builtin_amdgcn_mfma_f32_16x16x32_f16(a, b[3], acc_q[1],    0, 0, 0);
            acc_y[t]    = __builtin_amdgcn_mfma_f32_16x16x32_f16(a, b[4], acc_y[t],    0, 0, 0);
        }
        // vmcnt(0)+barrier: next chunk staged by ALL waves, cur buffer free for overwrite
        __syncthreads();
    }

    // ---------------- Epilogue (registers + shfl only) ----------------
    // C layout: element r holds sample row (quad*4 + r), column (n*16 + col).
    const float bias = (col < C_DIM) ? bfc[col] : 0.f;

    float outv[4];
    #pragma unroll
    for (int r = 0; r < 4; ++r) {
        const float qa = acc_q[0][r];     // q[sample][p=col]
        const float qb = acc_q[1][r];     // q[sample][p=16+col]
        float s0 = qa * acc_k[0][0][r] + qb * acc_k[0][1][r];
        float s1 = qa * acc_k[1][0][r] + qb * acc_k[1][1][r];
        float s2 = qa * acc_k[2][0][r] + qb * acc_k[2][1][r];
        #pragma unroll
        for (int msk = 1; msk <= 8; msk <<= 1) {
            s0 += __shfl_xor(s0, msk, 64);
            s1 += __shfl_xor(s1, msk, 64);
            s2 += __shfl_xor(s2, msk, 64);
        }
        const float mx = fmaxf(s0, fmaxf(s1, s2));
        const float e0 = __expf(s0 - mx);
        const float e1 = __expf(s1 - mx);
        const float e2 = __expf(s2 - mx);
        const float inv = 1.f / (e0 + e1 + e2);
        outv[r] = (e0 * acc_y[0][r] + e1 * acc_y[1][r] + e2 * acc_y[2][r]) * inv + bias;
    }
    if (col < C_DIM) {
        const int b0 = row_base + quad * 4;
        #pragma unroll
        for (int r = 0; r < 4; ++r)
            out[(size_t)(b0 + r) * C_DIM + col] = outv[r];
    }
}

extern "C" void kernel_launch(void* const* d_in, const int* in_sizes, int n_in,
                              void* d_out, int out_size, void* d_ws, size_t ws_size,
                              hipStream_t stream) {
    const float* x   = (const float*)d_in[0];
    const float* Wk  = (const float*)d_in[1];
    const float* Wv  = (const float*)d_in[2];
    const float* Wq  = (const float*)d_in[3];
    const float* Wfc = (const float*)d_in[4];
    const float* bfc = (const float*)d_in[5];
    _Float16* Wf = (_Float16*)d_ws;       // 3*80*512 halfs = 240 KB, fragment-ordered

    hipLaunchKernelGGL(build_weights, dim3(T_VIEWS * NROWS), dim3(D_DIM), 0, stream,
                       Wk, Wv, Wq, Wfc, Wf);

    const int B_TOTAL = in_sizes[0] / (T_VIEWS * D_DIM);      // 65536
    const int blocks = B_TOTAL / SAMPLES_PER_BLOCK;           // 1024
    hipLaunchKernelGGL(attn_fused, dim3(blocks), dim3(256), 0, stream,
                       x, Wf, bfc, (float*)d_out);
}